// Round 1
// baseline (300.731 us; speedup 1.0000x reference)
//
#include <hip/hip_runtime.h>

#define N_NODES   100000
#define N_EDGES   600000
#define D_FEAT    128
#define N_CLASSES 64

// ---------------------------------------------------------------------------
// Kernel 1: build Wt[k][c] (128 x 128): c<64 -> Wu[c][k] = W[c*256+k],
//           c>=64 -> Wv[c-64][k] = W[(c-64)*256+128+k]
// ---------------------------------------------------------------------------
__global__ __launch_bounds__(256) void build_wcat_t(const float* __restrict__ W,
                                                    float* __restrict__ Wt) {
    int idx = blockIdx.x * 256 + threadIdx.x;   // 0..16383
    int k = idx >> 7;
    int c = idx & 127;
    float v = (c < 64) ? W[c * 256 + k] : W[(c - 64) * 256 + 128 + k];
    Wt[k * 128 + c] = v;
}

// ---------------------------------------------------------------------------
// Kernel 2: P[n][0:128] = h[n] @ Wt  (P cols 0..63 = Wu proj, 64..127 = Wv proj)
// 64-row tile in LDS (pad 132: 2-way bank conflicts only -> free),
// each thread computes 4 rows x 8 channels, fp32 accumulation.
// ---------------------------------------------------------------------------
__global__ __launch_bounds__(256) void proj_kernel(const float* __restrict__ h,
                                                   const float* __restrict__ Wt,
                                                   float* __restrict__ P) {
    __shared__ float hs[64 * 132];   // 33792 B
    const int n0 = blockIdx.x * 64;
    const int t  = threadIdx.x;

    // stage 64 rows x 128 floats, coalesced float4 loads
#pragma unroll
    for (int i = 0; i < 8; ++i) {
        int idx  = t + i * 256;
        int row  = idx >> 5;          // 0..63
        int col4 = (idx & 31) << 2;   // 0,4,...,124
        int n = n0 + row;
        float4 v = make_float4(0.f, 0.f, 0.f, 0.f);
        if (n < N_NODES) v = *(const float4*)(h + (size_t)n * 128 + col4);
        *(float4*)(&hs[row * 132 + col4]) = v;
    }
    __syncthreads();

    const int tx = t & 15;    // channel group: c0 = tx*8
    const int ty = t >> 4;    // row group: m0 = ty*4
    const int c0 = tx * 8;
    const int m0 = ty * 4;

    float acc[4][8];
#pragma unroll
    for (int i = 0; i < 4; ++i)
#pragma unroll
        for (int j = 0; j < 8; ++j) acc[i][j] = 0.f;

    for (int k = 0; k < 128; k += 4) {
        float4 hv[4];
#pragma unroll
        for (int i = 0; i < 4; ++i)
            hv[i] = *(const float4*)(&hs[(m0 + i) * 132 + k]);
#pragma unroll
        for (int kk = 0; kk < 4; ++kk) {
            float4 wa = *(const float4*)(Wt + (k + kk) * 128 + c0);
            float4 wb = *(const float4*)(Wt + (k + kk) * 128 + c0 + 4);
            float w[8] = {wa.x, wa.y, wa.z, wa.w, wb.x, wb.y, wb.z, wb.w};
#pragma unroll
            for (int i = 0; i < 4; ++i) {
                float hk = ((const float*)&hv[i])[kk];
#pragma unroll
                for (int j = 0; j < 8; ++j) acc[i][j] += hk * w[j];
            }
        }
    }

#pragma unroll
    for (int i = 0; i < 4; ++i) {
        int n = n0 + m0 + i;
        if (n < N_NODES) {
            float4 o0 = make_float4(acc[i][0], acc[i][1], acc[i][2], acc[i][3]);
            float4 o1 = make_float4(acc[i][4], acc[i][5], acc[i][6], acc[i][7]);
            *(float4*)(P + (size_t)n * 128 + c0)     = o0;
            *(float4*)(P + (size_t)n * 128 + c0 + 4) = o1;
        }
    }
}

// ---------------------------------------------------------------------------
// Kernel 3: out[e][c] = P[src[e]][c] + P[dst[e]][64+c] + b[c]
// 16 lanes per edge, float4 per lane; writes fully coalesced.
// ---------------------------------------------------------------------------
__global__ __launch_bounds__(256) void edge_kernel(const int* __restrict__ src,
                                                   const int* __restrict__ dst,
                                                   const float* __restrict__ P,
                                                   const float* __restrict__ b,
                                                   float* __restrict__ out) {
    int g  = blockIdx.x * 256 + threadIdx.x;   // 0 .. 9,599,999 (exact grid)
    int e  = g >> 4;
    int c0 = (g & 15) << 2;
    int s = src[e];
    int d = dst[e];
    float4 ps = *(const float4*)(P + (size_t)s * 128 + c0);
    float4 pd = *(const float4*)(P + (size_t)d * 128 + 64 + c0);
    float4 bb = *(const float4*)(b + c0);
    float4 o;
    o.x = ps.x + pd.x + bb.x;
    o.y = ps.y + pd.y + bb.y;
    o.z = ps.z + pd.z + bb.z;
    o.w = ps.w + pd.w + bb.w;
    *(float4*)(out + (size_t)e * 64 + c0) = o;
}

// ---------------------------------------------------------------------------
// Fallback (only if ws too small): direct per-edge dot products, fp32.
// ---------------------------------------------------------------------------
__global__ __launch_bounds__(256) void direct_kernel(const float* __restrict__ h,
                                                     const int* __restrict__ src,
                                                     const int* __restrict__ dst,
                                                     const float* __restrict__ W,
                                                     const float* __restrict__ b,
                                                     float* __restrict__ out) {
    __shared__ float hcat[4][256];
    int t = threadIdx.x;
    int w = t >> 6, lane = t & 63;
    int e = blockIdx.x * 4 + w;
    bool valid = (e < N_EDGES);
    if (valid) {
        int s = src[e], d = dst[e];
        const float* p = (lane < 32) ? (h + (size_t)s * 128 + lane * 4)
                                     : (h + (size_t)d * 128 + (lane - 32) * 4);
        *(float4*)&hcat[w][lane * 4] = *(const float4*)p;
    }
    __syncthreads();
    if (!valid) return;
    int c = lane;   // 0..63
    float acc = 0.f;
    for (int k = 0; k < 256; k += 4) {
        float4 wv = *(const float4*)(W + c * 256 + k);
        acc += hcat[w][k]     * wv.x + hcat[w][k + 1] * wv.y
             + hcat[w][k + 2] * wv.z + hcat[w][k + 3] * wv.w;
    }
    out[(size_t)e * 64 + c] = acc + b[c];
}

extern "C" void kernel_launch(void* const* d_in, const int* in_sizes, int n_in,
                              void* d_out, int out_size, void* d_ws, size_t ws_size,
                              hipStream_t stream) {
    const float* h   = (const float*)d_in[0];
    const int*   src = (const int*)d_in[1];
    const int*   dst = (const int*)d_in[2];
    const float* W   = (const float*)d_in[3];
    const float* b   = (const float*)d_in[4];
    float* out = (float*)d_out;

    const size_t wt_bytes = 128 * 128 * sizeof(float);          // 64 KiB
    const size_t p_bytes  = (size_t)N_NODES * 128 * sizeof(float); // 51.2 MB
    if (ws_size >= wt_bytes + p_bytes) {
        float* Wt = (float*)d_ws;
        float* P  = (float*)((char*)d_ws + wt_bytes);
        build_wcat_t<<<64, 256, 0, stream>>>(W, Wt);
        proj_kernel<<<(N_NODES + 63) / 64, 256, 0, stream>>>(h, Wt, P);
        edge_kernel<<<(N_EDGES * 16) / 256, 256, 0, stream>>>(src, dst, P, b, out);
    } else {
        direct_kernel<<<(N_EDGES + 3) / 4, 256, 0, stream>>>(h, src, dst, W, b, out);
    }
}

// Round 2
// 267.219 us; speedup vs baseline: 1.1254x; 1.1254x over previous
//
#include <hip/hip_runtime.h>

#define N_NODES   100000
#define N_EDGES   600000
#define D_FEAT    128
#define N_CLASSES 64

typedef short bf16x8 __attribute__((ext_vector_type(8)));
typedef float f32x4  __attribute__((ext_vector_type(4)));

__device__ __forceinline__ unsigned short f2bf(float f) {
    unsigned int u = __float_as_uint(f);
    unsigned int r = (u + 0x7fffu + ((u >> 16) & 1u)) >> 16;   // RNE
    return (unsigned short)r;
}

// ---------------------------------------------------------------------------
// Kernel 1: Wc[c][k] (128x128 bf16): c<64 -> Wu[c][k]=W[c*256+k],
//           c>=64 -> Wv[c-64][k]=W[(c-64)*256+128+k]
// ---------------------------------------------------------------------------
__global__ __launch_bounds__(256) void build_wcat(const float* __restrict__ W,
                                                  unsigned short* __restrict__ Wc) {
    int idx = blockIdx.x * 256 + threadIdx.x;   // 0..16383
    int c = idx >> 7;
    int k = idx & 127;
    float v = (c < 64) ? W[c * 256 + k] : W[(c - 64) * 256 + 128 + k];
    Wc[c * 128 + k] = f2bf(v);
}

// ---------------------------------------------------------------------------
// Kernel 2 (MFMA): P[n][c] = sum_k h[n][k]*Wc[c][k]  (+ b[c] for c<64)
// One wave = 16 nodes x 128 channels. A-frags (h) held in regs across all
// 8 channel-tiles; 32x mfma_f32_16x16x32_bf16 per wave.
// A layout: m=lane&15, k=quad*8+j.  B layout: n=lane&15, k=quad*8+j.
// D layout: col(n)=lane&15, row(m)=quad*4+reg.
// ---------------------------------------------------------------------------
__global__ __launch_bounds__(256) void proj_mfma(const float* __restrict__ h,
                                                 const unsigned short* __restrict__ Wc,
                                                 const float* __restrict__ b,
                                                 float* __restrict__ P) {
    const int wave = (blockIdx.x * 256 + threadIdx.x) >> 6;
    const int lane = threadIdx.x & 63;
    const int n0   = wave * 16;                 // 100000 = 6250*16, no tail
    if (n0 >= N_NODES) return;
    const int m    = lane & 15;
    const int quad = lane >> 4;

    // A fragments: h[n0+m][ks*32 + quad*8 + 0..7], fp32 -> bf16
    bf16x8 afrag[4];
    const float* hrow = h + (size_t)(n0 + m) * 128 + quad * 8;
#pragma unroll
    for (int ks = 0; ks < 4; ++ks) {
        f32x4 v0 = __builtin_nontemporal_load((const f32x4*)(hrow + ks * 32));
        f32x4 v1 = __builtin_nontemporal_load((const f32x4*)(hrow + ks * 32 + 4));
        bf16x8 a;
        a[0] = (short)f2bf(v0[0]); a[1] = (short)f2bf(v0[1]);
        a[2] = (short)f2bf(v0[2]); a[3] = (short)f2bf(v0[3]);
        a[4] = (short)f2bf(v1[0]); a[5] = (short)f2bf(v1[1]);
        a[6] = (short)f2bf(v1[2]); a[7] = (short)f2bf(v1[3]);
        afrag[ks] = a;
    }

    f32x4 acc[8];
#pragma unroll
    for (int ct = 0; ct < 8; ++ct) acc[ct] = (f32x4){0.f, 0.f, 0.f, 0.f};

#pragma unroll
    for (int ct = 0; ct < 8; ++ct) {
        const unsigned short* wrow = Wc + (size_t)(ct * 16 + m) * 128 + quad * 8;
#pragma unroll
        for (int ks = 0; ks < 4; ++ks) {
            bf16x8 bfrag = *(const bf16x8*)(wrow + ks * 32);
            acc[ct] = __builtin_amdgcn_mfma_f32_16x16x32_bf16(afrag[ks], bfrag, acc[ct], 0, 0, 0);
        }
    }

#pragma unroll
    for (int ct = 0; ct < 8; ++ct) {
        int c = ct * 16 + m;
        float bias = (ct < 4) ? b[c] : 0.f;     // fold bias into Wu-half
        float* pout = P + (size_t)(n0 + quad * 4) * 128 + c;
#pragma unroll
        for (int r = 0; r < 4; ++r)
            pout[(size_t)r * 128] = acc[ct][r] + bias;
    }
}

// ---------------------------------------------------------------------------
// Kernel 3: out[e][c] = P[src[e]][c] + P[dst[e]][64+c]   (bias already in P)
// 16 lanes/edge, float4/lane; nontemporal stores keep P hot in L2/L3.
// ---------------------------------------------------------------------------
__global__ __launch_bounds__(256) void edge_kernel(const int* __restrict__ src,
                                                   const int* __restrict__ dst,
                                                   const float* __restrict__ P,
                                                   float* __restrict__ out) {
    int g  = blockIdx.x * 256 + threadIdx.x;    // exact grid: 600000*16
    int e  = g >> 4;
    int c0 = (g & 15) << 2;
    int s = src[e];
    int d = dst[e];
    f32x4 ps = *(const f32x4*)(P + (size_t)s * 128 + c0);
    f32x4 pd = *(const f32x4*)(P + (size_t)d * 128 + 64 + c0);
    f32x4 o  = ps + pd;
    __builtin_nontemporal_store(o, (f32x4*)(out + (size_t)e * 64 + c0));
}

// ---------------------------------------------------------------------------
// Fallback (ws too small): direct per-edge fp32 dot products.
// ---------------------------------------------------------------------------
__global__ __launch_bounds__(256) void direct_kernel(const float* __restrict__ h,
                                                     const int* __restrict__ src,
                                                     const int* __restrict__ dst,
                                                     const float* __restrict__ W,
                                                     const float* __restrict__ b,
                                                     float* __restrict__ out) {
    __shared__ float hcat[4][256];
    int t = threadIdx.x;
    int w = t >> 6, lane = t & 63;
    int e = blockIdx.x * 4 + w;
    bool valid = (e < N_EDGES);
    if (valid) {
        int s = src[e], d = dst[e];
        const float* p = (lane < 32) ? (h + (size_t)s * 128 + lane * 4)
                                     : (h + (size_t)d * 128 + (lane - 32) * 4);
        *(float4*)&hcat[w][lane * 4] = *(const float4*)p;
    }
    __syncthreads();
    if (!valid) return;
    int c = lane;
    float acc = 0.f;
    for (int k = 0; k < 256; k += 4) {
        float4 wv = *(const float4*)(W + c * 256 + k);
        acc += hcat[w][k] * wv.x + hcat[w][k + 1] * wv.y
             + hcat[w][k + 2] * wv.z + hcat[w][k + 3] * wv.w;
    }
    out[(size_t)e * 64 + c] = acc + b[c];
}

extern "C" void kernel_launch(void* const* d_in, const int* in_sizes, int n_in,
                              void* d_out, int out_size, void* d_ws, size_t ws_size,
                              hipStream_t stream) {
    const float* h   = (const float*)d_in[0];
    const int*   src = (const int*)d_in[1];
    const int*   dst = (const int*)d_in[2];
    const float* W   = (const float*)d_in[3];
    const float* b   = (const float*)d_in[4];
    float* out = (float*)d_out;

    const size_t wc_bytes = 128 * 128 * sizeof(unsigned short);      // 32 KiB
    const size_t p_bytes  = (size_t)N_NODES * 128 * sizeof(float);   // 51.2 MB
    if (ws_size >= wc_bytes + p_bytes) {
        unsigned short* Wc = (unsigned short*)d_ws;
        float* P = (float*)((char*)d_ws + wc_bytes);
        build_wcat<<<64, 256, 0, stream>>>(W, Wc);
        const int n_waves  = N_NODES / 16;                           // 6250
        const int n_blocks = (n_waves + 3) / 4;                      // 1563
        proj_mfma<<<n_blocks, 256, 0, stream>>>(h, Wc, b, P);
        edge_kernel<<<(N_EDGES * 16) / 256, 256, 0, stream>>>(src, dst, P, out);
    } else {
        direct_kernel<<<(N_EDGES + 3) / 4, 256, 0, stream>>>(h, src, dst, W, b, out);
    }
}

// Round 3
// 249.465 us; speedup vs baseline: 1.2055x; 1.0712x over previous
//
#include <hip/hip_runtime.h>

#define N_NODES   100000
#define N_EDGES   600000
#define D_FEAT    128
#define N_CLASSES 64

typedef short bf16x8 __attribute__((ext_vector_type(8)));
typedef float f32x4  __attribute__((ext_vector_type(4)));

__device__ __forceinline__ unsigned short f2bf(float f) {
    unsigned int u = __float_as_uint(f);
    unsigned int r = (u + 0x7fffu + ((u >> 16) & 1u)) >> 16;   // RNE
    return (unsigned short)r;
}
__device__ __forceinline__ float bf2f(unsigned short u) {
    return __uint_as_float((unsigned int)u << 16);
}

// ---------------------------------------------------------------------------
// Kernel 1: Wc[c][k] (128x128 bf16): c<64 -> Wu[c][k]=W[c*256+k],
//           c>=64 -> Wv[c-64][k]=W[(c-64)*256+128+k]
// ---------------------------------------------------------------------------
__global__ __launch_bounds__(256) void build_wcat(const float* __restrict__ W,
                                                  unsigned short* __restrict__ Wc) {
    int idx = blockIdx.x * 256 + threadIdx.x;   // 0..16383
    int c = idx >> 7;
    int k = idx & 127;
    float v = (c < 64) ? W[c * 256 + k] : W[(c - 64) * 256 + 128 + k];
    Wc[c * 128 + k] = f2bf(v);
}

// ---------------------------------------------------------------------------
// Kernel 2 (MFMA): P[n][c] = sum_k h[n][k]*Wc[c][k]  (+ b[c] for c<64), bf16 out
// A = Wc (M=channels), B = h (N=nodes):
//   A frag: ch = ct*16 + (lane&15), k = quad*8+j
//   B frag: node = n0 + (lane&15),  k = quad*8+j
//   D: row=channel = ct*16 + quad*4 + r, col=node = n0 + (lane&15)
// -> epilogue: per lane, 4 consecutive channels for one node = ushort4 store.
// h loads are CACHED (not nontemporal): each 128B line shared by 4 lanes.
// ---------------------------------------------------------------------------
__global__ __launch_bounds__(256) void proj_mfma(const float* __restrict__ h,
                                                 const unsigned short* __restrict__ Wc,
                                                 const float* __restrict__ b,
                                                 unsigned short* __restrict__ P) {
    const int wave = (blockIdx.x * 256 + threadIdx.x) >> 6;
    const int lane = threadIdx.x & 63;
    const int n0   = wave * 16;                 // 100000 = 6250*16, no tail
    if (n0 >= N_NODES) return;
    const int m    = lane & 15;
    const int quad = lane >> 4;

    // B fragments: h[n0+m][ks*32 + quad*8 + 0..7], fp32 -> bf16 (cached loads)
    bf16x8 hfrag[4];
    const float* hrow = h + (size_t)(n0 + m) * 128 + quad * 8;
#pragma unroll
    for (int ks = 0; ks < 4; ++ks) {
        f32x4 v0 = *(const f32x4*)(hrow + ks * 32);
        f32x4 v1 = *(const f32x4*)(hrow + ks * 32 + 4);
        bf16x8 a;
        a[0] = (short)f2bf(v0[0]); a[1] = (short)f2bf(v0[1]);
        a[2] = (short)f2bf(v0[2]); a[3] = (short)f2bf(v0[3]);
        a[4] = (short)f2bf(v1[0]); a[5] = (short)f2bf(v1[1]);
        a[6] = (short)f2bf(v1[2]); a[7] = (short)f2bf(v1[3]);
        hfrag[ks] = a;
    }

    f32x4 acc[8];
#pragma unroll
    for (int ct = 0; ct < 8; ++ct) acc[ct] = (f32x4){0.f, 0.f, 0.f, 0.f};

#pragma unroll
    for (int ct = 0; ct < 8; ++ct) {
        const unsigned short* wrow = Wc + (size_t)(ct * 16 + m) * 128 + quad * 8;
#pragma unroll
        for (int ks = 0; ks < 4; ++ks) {
            bf16x8 wfrag = *(const bf16x8*)(wrow + ks * 32);
            acc[ct] = __builtin_amdgcn_mfma_f32_16x16x32_bf16(wfrag, hfrag[ks], acc[ct], 0, 0, 0);
        }
    }

    const int node = n0 + m;
    unsigned short* prow = P + (size_t)node * 128;
#pragma unroll
    for (int ct = 0; ct < 8; ++ct) {
        const int cb = ct * 16 + quad * 4;      // channel base, multiple of 4
        float v[4];
        if (cb < 64) {                          // fold bias into Wu half
            f32x4 bb = *(const f32x4*)(b + cb);
#pragma unroll
            for (int r = 0; r < 4; ++r) v[r] = acc[ct][r] + bb[r];
        } else {
#pragma unroll
            for (int r = 0; r < 4; ++r) v[r] = acc[ct][r];
        }
        ushort4 pk;
        pk.x = f2bf(v[0]); pk.y = f2bf(v[1]);
        pk.z = f2bf(v[2]); pk.w = f2bf(v[3]);
        *(ushort4*)(prow + cb) = pk;
    }
}

// ---------------------------------------------------------------------------
// Kernel 3: out[e][c] = P[src[e]][c] + P[dst[e]][64+c]   (bias already in P)
// 16 lanes/edge, ushort4 (8B) gather loads, f32x4 nontemporal stores.
// ---------------------------------------------------------------------------
__global__ __launch_bounds__(256) void edge_kernel(const int* __restrict__ src,
                                                   const int* __restrict__ dst,
                                                   const unsigned short* __restrict__ P,
                                                   float* __restrict__ out) {
    int g  = blockIdx.x * 256 + threadIdx.x;    // exact grid: 600000*16
    int e  = g >> 4;
    int c0 = (g & 15) << 2;
    int s = src[e];
    int d = dst[e];
    ushort4 us = *(const ushort4*)(P + (size_t)s * 128 + c0);
    ushort4 ud = *(const ushort4*)(P + (size_t)d * 128 + 64 + c0);
    f32x4 o;
    o[0] = bf2f(us.x) + bf2f(ud.x);
    o[1] = bf2f(us.y) + bf2f(ud.y);
    o[2] = bf2f(us.z) + bf2f(ud.z);
    o[3] = bf2f(us.w) + bf2f(ud.w);
    __builtin_nontemporal_store(o, (f32x4*)(out + (size_t)e * 64 + c0));
}

// ---------------------------------------------------------------------------
// Fallback (ws too small): direct per-edge fp32 dot products.
// ---------------------------------------------------------------------------
__global__ __launch_bounds__(256) void direct_kernel(const float* __restrict__ h,
                                                     const int* __restrict__ src,
                                                     const int* __restrict__ dst,
                                                     const float* __restrict__ W,
                                                     const float* __restrict__ b,
                                                     float* __restrict__ out) {
    __shared__ float hcat[4][256];
    int t = threadIdx.x;
    int w = t >> 6, lane = t & 63;
    int e = blockIdx.x * 4 + w;
    bool valid = (e < N_EDGES);
    if (valid) {
        int s = src[e], d = dst[e];
        const float* p = (lane < 32) ? (h + (size_t)s * 128 + lane * 4)
                                     : (h + (size_t)d * 128 + (lane - 32) * 4);
        *(float4*)&hcat[w][lane * 4] = *(const float4*)p;
    }
    __syncthreads();
    if (!valid) return;
    int c = lane;
    float acc = 0.f;
    for (int k = 0; k < 256; k += 4) {
        float4 wv = *(const float4*)(W + c * 256 + k);
        acc += hcat[w][k] * wv.x + hcat[w][k + 1] * wv.y
             + hcat[w][k + 2] * wv.z + hcat[w][k + 3] * wv.w;
    }
    out[(size_t)e * 64 + c] = acc + b[c];
}

extern "C" void kernel_launch(void* const* d_in, const int* in_sizes, int n_in,
                              void* d_out, int out_size, void* d_ws, size_t ws_size,
                              hipStream_t stream) {
    const float* h   = (const float*)d_in[0];
    const int*   src = (const int*)d_in[1];
    const int*   dst = (const int*)d_in[2];
    const float* W   = (const float*)d_in[3];
    const float* b   = (const float*)d_in[4];
    float* out = (float*)d_out;

    const size_t wc_bytes = 128 * 128 * sizeof(unsigned short);              // 32 KiB
    const size_t p_bytes  = (size_t)N_NODES * 128 * sizeof(unsigned short);  // 25.6 MB
    if (ws_size >= wc_bytes + p_bytes) {
        unsigned short* Wc = (unsigned short*)d_ws;
        unsigned short* P  = (unsigned short*)((char*)d_ws + wc_bytes);
        build_wcat<<<64, 256, 0, stream>>>(W, Wc);
        const int n_waves  = N_NODES / 16;                                   // 6250
        const int n_blocks = (n_waves + 3) / 4;                              // 1563
        proj_mfma<<<n_blocks, 256, 0, stream>>>(h, Wc, b, P);
        edge_kernel<<<(N_EDGES * 16) / 256, 256, 0, stream>>>(src, dst, P, out);
    } else {
        direct_kernel<<<(N_EDGES + 3) / 4, 256, 0, stream>>>(h, src, dst, W, b, out);
    }
}